// Round 4
// baseline (309.029 us; speedup 1.0000x reference)
//
#include <hip/hip_runtime.h>
#include <hip/hip_cooperative_groups.h>
#include <math.h>

namespace cg = cooperative_groups;

#define Bg   64
#define Nn   1024
#define Dd   256
#define EPG  16384               // edges per graph
#define NT   (Bg * Nn)           // 65536 nodes
#define Kk   512

// d_out float offsets
#define OFF_DIS   0
#define OFF_COM   8388608
#define OFF_PERM  16777216
#define OFF_PCOM  16809984
#define OFF_SOFT  16842752

// ws byte offsets
#define WS_H0     0
#define WS_SFLAT  (NT * 4)
#define WS_GPART  (NT * 4 * 2)                 // 256 blocks * 256 floats = 256 KB
#define WS_REDM   (WS_GPART + 1024 * 256 * 4)  // 64 floats
#define WS_REDS   (WS_REDM + 256)              // 64 floats
#define WS_C0     (WS_REDS + 256)              // 256 floats
#define WS_C1     (WS_C0 + 1024)               // 256 floats
#define WS_PERMI  (WS_C1 + 1024)
#define WS_PCOMI  (WS_PERMI + 32768 * 4)
#define WS_SGCN   (WS_PCOMI + 32768 * 4)       // NT floats

// ---------------------------------------------------------------------------
// Single cooperative kernel: 256 blocks x 1024 threads (1 block/CU).
// Phases (grid.sync between): col+h0 -> edges/sgcn + centers -> scores ->
// per-graph topk/sort/softmax-partials -> gather-write + softmax.
// All phase bodies are transplants of previously harness-verified kernels.
// ---------------------------------------------------------------------------
__global__ __launch_bounds__(1024) void k_fused(
        const float* __restrict__ f, const float* __restrict__ W,
        const int* __restrict__ src, const int* __restrict__ dst,
        const int* __restrict__ label, const float* __restrict__ b,
        const float* __restrict__ lw, const float* __restrict__ lb,
        float* __restrict__ h0, float* __restrict__ gpart,
        float* __restrict__ c0, float* __restrict__ c1,
        float* __restrict__ sgcn, float* __restrict__ sflat,
        int* __restrict__ permI, int* __restrict__ pcomI,
        float* __restrict__ redM, float* __restrict__ redS,
        float* __restrict__ out) {
    __shared__ alignas(16) char smem[81920];   // 80 KB phase union
    __shared__ int   swave[8];
    __shared__ float sred[33];
    __shared__ float sMS[2];

    cg::grid_group grid = cg::this_grid();
    int blk = blockIdx.x, t = threadIdx.x;

    // ---------------- phase 1: column sums + h0 = f @ W (256 rows/block) ---
    {
        float4* scol4 = (float4*)smem;          // 64 groups x 64 float4 = 64 KB
        int gid = t >> 4, sub = t & 15;
        int base = blk * 256 + gid * 4;
        const float4* f4 = (const float4*)f;
        const float4* W4 = (const float4*)W;
        float4 w[4];
        #pragma unroll
        for (int it = 0; it < 4; ++it) w[it] = W4[it * 16 + sub];
        float4 cs[4];
        #pragma unroll
        for (int it = 0; it < 4; ++it) cs[it] = make_float4(0.f, 0.f, 0.f, 0.f);
        #pragma unroll
        for (int kb = 0; kb < 2; ++kb) {
            float4 v[2][4];
            #pragma unroll
            for (int k = 0; k < 2; ++k) {
                size_t bofs = (size_t)(base + kb * 2 + k) * 64;
                #pragma unroll
                for (int it = 0; it < 4; ++it) v[k][it] = f4[bofs + it * 16 + sub];
            }
            #pragma unroll
            for (int k = 0; k < 2; ++k) {
                float d = 0.f;
                #pragma unroll
                for (int it = 0; it < 4; ++it) {
                    cs[it].x += v[k][it].x; cs[it].y += v[k][it].y;
                    cs[it].z += v[k][it].z; cs[it].w += v[k][it].w;
                    d += v[k][it].x * w[it].x + v[k][it].y * w[it].y
                       + v[k][it].z * w[it].z + v[k][it].w * w[it].w;
                }
                #pragma unroll
                for (int o = 1; o < 16; o <<= 1) d += __shfl_xor(d, o);
                if (sub == 0) h0[base + kb * 2 + k] = d;
            }
        }
        #pragma unroll
        for (int it = 0; it < 4; ++it) scol4[gid * 64 + it * 16 + sub] = cs[it];
        __syncthreads();
        if (t < 256) {
            float4 s = make_float4(0.f, 0.f, 0.f, 0.f);
            #pragma unroll
            for (int g2 = 0; g2 < 64; ++g2) {
                float4 u = scol4[g2 * 64 + t];
                s.x += u.x; s.y += u.y; s.z += u.z; s.w += u.w;
            }
            ((float4*)gpart)[blk * 64 + t] = s;
        }
    }
    grid.sync();

    // ---------------- phase 2: edges (blocks 0..63) + centers (block 64) ---
    if (blk < 64) {
        uint4* ep4 = (uint4*)smem;              // 64 KB
        int*   sdo = (int*)(smem + 65536);      // 4 KB
        int*   sdi = (int*)(smem + 69632);      // 4 KB
        float* shn = (float*)(smem + 73728);    // 4 KB
        float* ssc = (float*)(smem + 77824);    // 4 KB
        int g = blk;
        sdo[t] = 0; sdi[t] = 0;
        __syncthreads();
        {
            const int4* s4 = (const int4*)(src + g * EPG);
            const int4* d4 = (const int4*)(dst + g * EPG);
            #pragma unroll
            for (int i = t; i < EPG / 4; i += 1024) {
                int4 ss = s4[i];
                int4 dd = d4[i];
                int s0 = ss.x & (Nn - 1), s1 = ss.y & (Nn - 1), s2 = ss.z & (Nn - 1), s3 = ss.w & (Nn - 1);
                int e0 = dd.x & (Nn - 1), e1 = dd.y & (Nn - 1), e2 = dd.z & (Nn - 1), e3 = dd.w & (Nn - 1);
                uint4 pk;
                pk.x = (unsigned)(s0 | (e0 << 16));
                pk.y = (unsigned)(s1 | (e1 << 16));
                pk.z = (unsigned)(s2 | (e2 << 16));
                pk.w = (unsigned)(s3 | (e3 << 16));
                ep4[i] = pk;
                atomicAdd(&sdo[s0], 1); atomicAdd(&sdo[s1], 1);
                atomicAdd(&sdo[s2], 1); atomicAdd(&sdo[s3], 1);
                atomicAdd(&sdi[e0], 1); atomicAdd(&sdi[e1], 1);
                atomicAdd(&sdi[e2], 1); atomicAdd(&sdi[e3], 1);
            }
        }
        __syncthreads();
        {
            int dg = sdo[t]; if (dg < 1) dg = 1;
            shn[t] = h0[g * Nn + t] / sqrtf((float)dg);
            ssc[t] = 0.f;
        }
        __syncthreads();
        #pragma unroll
        for (int i = t; i < EPG / 4; i += 1024) {
            uint4 pk = ep4[i];
            atomicAdd(&ssc[pk.x >> 16], shn[pk.x & 0xFFFF]);
            atomicAdd(&ssc[pk.y >> 16], shn[pk.y & 0xFFFF]);
            atomicAdd(&ssc[pk.z >> 16], shn[pk.z & 0xFFFF]);
            atomicAdd(&ssc[pk.w >> 16], shn[pk.w & 0xFFFF]);
        }
        __syncthreads();
        {
            int dg = sdi[t]; if (dg < 1) dg = 1;
            sgcn[g * Nn + t] = ssc[t] / sqrtf((float)dg) + b[0];
        }
    } else if (blk == 64) {
        float* sc0 = (float*)smem;
        float* sc1 = (float*)(smem + 4096);
        int col = t & 255, chunk = t >> 8;      // 4 chunks x 16 graphs
        float a0 = 0.f, a1 = 0.f;
        for (int gg = chunk * 16; gg < chunk * 16 + 16; ++gg) {
            float v = 0.f;
            #pragma unroll
            for (int p = 0; p < 4; ++p) v += gpart[(gg * 4 + p) * Dd + col];
            if (label[gg]) a1 += v; else a0 += v;
        }
        sc0[t] = a0; sc1[t] = a1;
        __syncthreads();
        if (t < Dd) {
            int n1 = 0;
            for (int gg = 0; gg < Bg; ++gg) n1 += label[gg];
            float fn1 = fmaxf((float)n1, 1.f);
            float fn0 = fmaxf((float)(Bg - n1), 1.f);
            float s0 = sc0[t] + sc0[256 + t] + sc0[512 + t] + sc0[768 + t];
            float s1 = sc1[t] + sc1[256 + t] + sc1[512 + t] + sc1[768 + t];
            c0[t] = s0 * (1.f / (float)Nn) / fn0;
            c1[t] = s1 * (1.f / (float)Nn) / fn1;
        }
    }
    grid.sync();

    // ---------------- phase 3: distances + score combine (256 rows/block) --
    {
        int gid = t >> 4, sub = t & 15;
        int row0 = blk * 256 + gid * 4;
        int g = row0 >> 10;
        const float4* f4 = (const float4*)f;
        float4 c0r[4], c1r[4];
        #pragma unroll
        for (int it = 0; it < 4; ++it) {
            c0r[it] = ((const float4*)c0)[it * 16 + sub];
            c1r[it] = ((const float4*)c1)[it * 16 + sub];
        }
        float sgn = label[g] ? 1.f : -1.f;
        float lw0 = lw[0], lw1 = lw[1], lb0 = lb[0];
        #pragma unroll
        for (int rb = 0; rb < 2; ++rb) {
            float4 v[2][4];
            #pragma unroll
            for (int r = 0; r < 2; ++r) {
                size_t bofs = (size_t)(row0 + rb * 2 + r) * 64;
                #pragma unroll
                for (int it = 0; it < 4; ++it) v[r][it] = f4[bofs + it * 16 + sub];
            }
            #pragma unroll
            for (int r = 0; r < 2; ++r) {
                float a0 = 0.f, a1 = 0.f;
                #pragma unroll
                for (int it = 0; it < 4; ++it) {
                    float dx;
                    dx = v[r][it].x - c0r[it].x; a0 += dx * dx;
                    dx = v[r][it].y - c0r[it].y; a0 += dx * dx;
                    dx = v[r][it].z - c0r[it].z; a0 += dx * dx;
                    dx = v[r][it].w - c0r[it].w; a0 += dx * dx;
                    dx = v[r][it].x - c1r[it].x; a1 += dx * dx;
                    dx = v[r][it].y - c1r[it].y; a1 += dx * dx;
                    dx = v[r][it].z - c1r[it].z; a1 += dx * dx;
                    dx = v[r][it].w - c1r[it].w; a1 += dx * dx;
                }
                #pragma unroll
                for (int o = 1; o < 16; o <<= 1) {
                    a0 += __shfl_xor(a0, o);
                    a1 += __shfl_xor(a1, o);
                }
                if (sub == 0) {
                    int row = row0 + rb * 2 + r;
                    float sdist = (sqrtf(a0) - sqrtf(a1)) * sgn;
                    sflat[row] = sgcn[row] * lw0 + sdist * lw1 + lb0;
                }
            }
        }
    }
    grid.sync();

    // ---------------- phase 4: per-graph bitonic topk + softmax partials ---
    if (blk < 64) {
        unsigned long long* sk = (unsigned long long*)smem;  // 8 KB
        int* sflag = (int*)(smem + 8192);                    // 4 KB
        int g = blk;
        int lane = t & 63, w16 = t >> 6;
        float v = sflat[g * Nn + t];
        {
            unsigned u = __float_as_uint(v);
            unsigned ox = u ^ ((u >> 31) ? 0xFFFFFFFFu : 0x80000000u);
            sk[t] = ((unsigned long long)ox << 32) | (unsigned)(1023 - t);
        }
        __syncthreads();
        for (int k = 2; k <= 1024; k <<= 1) {
            for (int j = k >> 1; j > 0; j >>= 1) {
                if (t < 512) {
                    int l = ((t & ~(j - 1)) << 1) | (t & (j - 1));
                    int r = l | j;
                    unsigned long long A = sk[l], Bk = sk[r];
                    bool up = ((l & k) == 0);
                    if ((A < Bk) == up) { sk[l] = Bk; sk[r] = A; }
                }
                __syncthreads();
            }
        }
        sflag[t] = 1;
        __syncthreads();
        if (t < 512) {
            int loc = 1023 - (int)(sk[t] & 0xFFFFFFFFu);
            sflag[loc] = 0;
            int gi = g * Nn + loc;
            permI[g * Kk + t] = gi;
            out[OFF_PERM + g * Kk + t] = (float)gi;
        }
        __syncthreads();
        int f0 = 0, f1 = 0, f2 = 0, inc = 0;
        if (t < 512) {
            f0 = sflag[2 * t]; f1 = sflag[2 * t + 1];
            f2 = f0 + f1; inc = f2;
            for (int o = 1; o < 64; o <<= 1) {
                int y = __shfl_up(inc, o);
                if (lane >= o) inc += y;
            }
            if (lane == 63) swave[w16] = inc;
        }
        __syncthreads();
        if (t < 8) {
            int a = swave[t];
            for (int o = 1; o < 8; o <<= 1) {
                int y = __shfl_up(a, o);
                if (t >= o) a += y;
            }
            swave[t] = a;
        }
        __syncthreads();
        if (t < 512) {
            int basep = ((w16 > 0) ? swave[w16 - 1] : 0) + (inc - f2);
            if (f0) {
                int gi = g * Nn + 2 * t;
                pcomI[g * Kk + basep] = gi;
                out[OFF_PCOM + g * Kk + basep] = (float)gi;
            }
            if (f1) {
                int pos = basep + f0;
                int gi = g * Nn + 2 * t + 1;
                pcomI[g * Kk + pos] = gi;
                out[OFF_PCOM + g * Kk + pos] = (float)gi;
            }
        }
        // softmax partials (per-graph max and sum)
        float m = v;
        for (int o = 32; o > 0; o >>= 1) m = fmaxf(m, __shfl_xor(m, o));
        if (lane == 0) sred[w16] = m;
        __syncthreads();
        if (t < 16) {
            float a = sred[t];
            for (int o = 8; o > 0; o >>= 1) a = fmaxf(a, __shfl_xor(a, o));
            if (t == 0) sred[32] = a;
        }
        __syncthreads();
        float M = sred[32];
        float s = expf(v - M);
        for (int o = 32; o > 0; o >>= 1) s += __shfl_xor(s, o);
        if (lane == 0) sred[16 + w16] = s;
        __syncthreads();
        if (t < 16) {
            float a = sred[16 + t];
            for (int o = 8; o > 0; o >>= 1) a += __shfl_xor(a, o);
            if (t == 0) { redM[g] = M; redS[g] = a; }
        }
    }
    grid.sync();

    // ---------------- phase 5: gather * tanh + softmax write (256 rows/blk)-
    {
        if (t < 64) {
            float m = redM[t];
            float mm = m;
            for (int o = 32; o > 0; o >>= 1) mm = fmaxf(mm, __shfl_xor(mm, o));
            float s = redS[t] * expf(m - mm);
            for (int o = 32; o > 0; o >>= 1) s += __shfl_xor(s, o);
            if (t == 0) { sMS[0] = mm; sMS[1] = s; }
        }
        __syncthreads();
        float M = sMS[0], S = sMS[1];
        if (t < 256) {
            int i = blk * 256 + t;
            out[OFF_SOFT + i] = expf(sflat[i] - M) / S;
        }
        int w = t >> 6, lane = t & 63;
        const float4* f4 = (const float4*)f;
        float4* o4 = (float4*)out;
        #pragma unroll
        for (int bb = 0; bb < 4; ++bb) {
            int j0 = blk * 256 + w * 16 + bb * 4;
            int rows[4];
            float tv[4];
            #pragma unroll
            for (int i = 0; i < 4; ++i) {
                int j = j0 + i;
                rows[i] = (j < 32768) ? permI[j] : pcomI[j - 32768];
            }
            #pragma unroll
            for (int i = 0; i < 4; ++i) tv[i] = tanhf(sflat[rows[i]]);
            #pragma unroll
            for (int i = 0; i < 4; ++i) {
                float4 v = f4[(size_t)rows[i] * 64 + lane];
                o4[(size_t)(j0 + i) * 64 + lane] =
                    make_float4(v.x * tv[i], v.y * tv[i], v.z * tv[i], v.w * tv[i]);
            }
        }
    }
}

extern "C" void kernel_launch(void* const* d_in, const int* in_sizes, int n_in,
                              void* d_out, int out_size, void* d_ws, size_t ws_size,
                              hipStream_t stream) {
    const float* feature = (const float*)d_in[0];
    const int*   src     = (const int*)d_in[1];
    const int*   dst     = (const int*)d_in[2];
    const int*   label   = (const int*)d_in[3];
    const float* W       = (const float*)d_in[4];
    const float* b       = (const float*)d_in[5];
    const float* lw      = (const float*)d_in[6];
    const float* lb      = (const float*)d_in[7];
    float* out = (float*)d_out;
    char*  ws  = (char*)d_ws;

    float* h0    = (float*)(ws + WS_H0);
    float* sflat = (float*)(ws + WS_SFLAT);
    float* gpart = (float*)(ws + WS_GPART);
    float* redM  = (float*)(ws + WS_REDM);
    float* redS  = (float*)(ws + WS_REDS);
    float* c0    = (float*)(ws + WS_C0);
    float* c1    = (float*)(ws + WS_C1);
    int*   permI = (int*)(ws + WS_PERMI);
    int*   pcomI = (int*)(ws + WS_PCOMI);
    float* sgcn  = (float*)(ws + WS_SGCN);

    void* args[] = {
        (void*)&feature, (void*)&W, (void*)&src, (void*)&dst, (void*)&label,
        (void*)&b, (void*)&lw, (void*)&lb,
        (void*)&h0, (void*)&gpart, (void*)&c0, (void*)&c1,
        (void*)&sgcn, (void*)&sflat, (void*)&permI, (void*)&pcomI,
        (void*)&redM, (void*)&redS, (void*)&out
    };
    hipLaunchCooperativeKernel((const void*)k_fused, dim3(256), dim3(1024),
                               args, 0, stream);
}

// Round 5
// 199.438 us; speedup vs baseline: 1.5495x; 1.5495x over previous
//
#include <hip/hip_runtime.h>
#include <math.h>

#define Bg   64
#define Nn   1024
#define Dd   256
#define EPG  16384               // edges per graph
#define NT   (Bg * Nn)           // 65536 nodes
#define Kk   512

// d_out float offsets
#define OFF_DIS   0
#define OFF_COM   8388608
#define OFF_PERM  16777216
#define OFF_PCOM  16809984
#define OFF_SOFT  16842752

// ws byte offsets (~3 MB used)
#define WS_H0     0
#define WS_SFLAT  (NT * 4)
#define WS_GPART  (NT * 4 * 2)                 // 1024 blocks * 256 floats = 1 MB
#define WS_REDM   (WS_GPART + 1024 * 256 * 4)  // 64 floats
#define WS_REDS   (WS_REDM + 256)              // 64 floats
#define WS_C0     (WS_REDS + 256)              // 256 floats
#define WS_C1     (WS_C0 + 1024)               // 256 floats
#define WS_PERMI  (WS_C1 + 1024)
#define WS_PCOMI  (WS_PERMI + 32768 * 4)
#define WS_SGCN   (WS_PCOMI + 32768 * 4)       // NT floats

// ---------------------------------------------------------------------------
// K1: 1024 blocks x 256 threads, 64 rows/block. 16-lane group per row-quad.
// (Verified round-3 code, unchanged.)
// ---------------------------------------------------------------------------
__global__ __launch_bounds__(256) void k_col(
        const float* __restrict__ f, const float* __restrict__ W,
        float* __restrict__ gpart, float* __restrict__ h0) {
    __shared__ float4 scol4[1024];              // 16 groups x 64 float4-cols (16 KB)
    int blk = blockIdx.x, t = threadIdx.x;
    int gid = t >> 4, sub = t & 15;
    int base = blk * 64 + gid * 4;
    const float4* f4 = (const float4*)f;
    const float4* W4 = (const float4*)W;
    float4 w[4];
    #pragma unroll
    for (int it = 0; it < 4; ++it) w[it] = W4[it * 16 + sub];
    float4 cs[4];
    #pragma unroll
    for (int it = 0; it < 4; ++it) cs[it] = make_float4(0.f, 0.f, 0.f, 0.f);
    float4 v[4][4];
    #pragma unroll
    for (int k = 0; k < 4; ++k) {
        size_t bofs = (size_t)(base + k) * 64;
        #pragma unroll
        for (int it = 0; it < 4; ++it) v[k][it] = f4[bofs + it * 16 + sub];
    }
    #pragma unroll
    for (int k = 0; k < 4; ++k) {
        float d = 0.f;
        #pragma unroll
        for (int it = 0; it < 4; ++it) {
            cs[it].x += v[k][it].x; cs[it].y += v[k][it].y;
            cs[it].z += v[k][it].z; cs[it].w += v[k][it].w;
            d += v[k][it].x * w[it].x + v[k][it].y * w[it].y
               + v[k][it].z * w[it].z + v[k][it].w * w[it].w;
        }
        #pragma unroll
        for (int o = 1; o < 16; o <<= 1) d += __shfl_xor(d, o);
        if (sub == 0) h0[base + k] = d;
    }
    #pragma unroll
    for (int it = 0; it < 4; ++it) scol4[gid * 64 + it * 16 + sub] = cs[it];
    __syncthreads();
    if (t < 64) {
        float4 s = make_float4(0.f, 0.f, 0.f, 0.f);
        #pragma unroll
        for (int g2 = 0; g2 < 16; ++g2) {
            float4 u = scol4[g2 * 64 + t];
            s.x += u.x; s.y += u.y; s.z += u.z; s.w += u.w;
        }
        ((float4*)(gpart + blk * Dd))[t] = s;
    }
}

// ---------------------------------------------------------------------------
// K2: 64 blocks x 1024 threads — one block per graph. LDS-only edge pipeline.
// Block 0 also computes class centers. (Verified round-3 code, unchanged.)
// ---------------------------------------------------------------------------
__global__ __launch_bounds__(1024) void k_edge(
        const int* __restrict__ src, const int* __restrict__ dst,
        const int* __restrict__ label, const float* __restrict__ h0,
        const float* __restrict__ gpart, const float* __restrict__ b,
        float* __restrict__ sgcn, float* __restrict__ c0, float* __restrict__ c1) {
    __shared__ uint4 ep4[4096];                 // 64 KB packed edges (src | dst<<16)
    __shared__ int   sdo[1024];                 // deg_out
    __shared__ int   sdi[1024];                 // deg_in
    __shared__ float shn[1024];                 // h0 * ns
    __shared__ float ssc[1024];                 // agg
    __shared__ float sc0[1024];                 // center partials (block 0 only)
    __shared__ float sc1[1024];

    int g = blockIdx.x, t = threadIdx.x;
    sdo[t] = 0; sdi[t] = 0;

    if (g == 0) {
        // centers: 4 chunks x 16 graphs, coalesced over columns
        int col = t & 255, chunk = t >> 8;
        float a0 = 0.f, a1 = 0.f;
        for (int gg = chunk * 16; gg < chunk * 16 + 16; ++gg) {
            float v = 0.f;
            #pragma unroll
            for (int p = 0; p < 16; ++p) v += gpart[(gg * 16 + p) * Dd + col];
            if (label[gg]) a1 += v; else a0 += v;
        }
        sc0[t] = a0; sc1[t] = a1;
        __syncthreads();
        if (t < Dd) {
            int n1 = 0;
            for (int gg = 0; gg < Bg; ++gg) n1 += label[gg];
            float fn1 = fmaxf((float)n1, 1.f);
            float fn0 = fmaxf((float)(Bg - n1), 1.f);
            float s0 = sc0[t] + sc0[256 + t] + sc0[512 + t] + sc0[768 + t];
            float s1 = sc1[t] + sc1[256 + t] + sc1[512 + t] + sc1[768 + t];
            c0[t] = s0 * (1.f / (float)Nn) / fn0;
            c1[t] = s1 * (1.f / (float)Nn) / fn1;
        }
    }
    __syncthreads();

    // phase 1: load raw edges, pack into LDS, count degrees
    {
        const int4* s4 = (const int4*)(src + g * EPG);
        const int4* d4 = (const int4*)(dst + g * EPG);
        #pragma unroll
        for (int i = t; i < EPG / 4; i += 1024) {
            int4 ss = s4[i];
            int4 dd = d4[i];
            int s0 = ss.x & (Nn - 1), s1 = ss.y & (Nn - 1), s2 = ss.z & (Nn - 1), s3 = ss.w & (Nn - 1);
            int e0 = dd.x & (Nn - 1), e1 = dd.y & (Nn - 1), e2 = dd.z & (Nn - 1), e3 = dd.w & (Nn - 1);
            uint4 pk;
            pk.x = (unsigned)(s0 | (e0 << 16));
            pk.y = (unsigned)(s1 | (e1 << 16));
            pk.z = (unsigned)(s2 | (e2 << 16));
            pk.w = (unsigned)(s3 | (e3 << 16));
            ep4[i] = pk;
            atomicAdd(&sdo[s0], 1); atomicAdd(&sdo[s1], 1);
            atomicAdd(&sdo[s2], 1); atomicAdd(&sdo[s3], 1);
            atomicAdd(&sdi[e0], 1); atomicAdd(&sdi[e1], 1);
            atomicAdd(&sdi[e2], 1); atomicAdd(&sdi[e3], 1);
        }
    }
    __syncthreads();

    // phase 2: shn = h0 * deg_out^-1/2 ; zero agg
    {
        int dg = sdo[t]; if (dg < 1) dg = 1;
        shn[t] = h0[g * Nn + t] / sqrtf((float)dg);
        ssc[t] = 0.f;
    }
    __syncthreads();

    // phase 3: normalized scatter
    #pragma unroll
    for (int i = t; i < EPG / 4; i += 1024) {
        uint4 pk = ep4[i];
        atomicAdd(&ssc[pk.x >> 16], shn[pk.x & 0xFFFF]);
        atomicAdd(&ssc[pk.y >> 16], shn[pk.y & 0xFFFF]);
        atomicAdd(&ssc[pk.z >> 16], shn[pk.z & 0xFFFF]);
        atomicAdd(&ssc[pk.w >> 16], shn[pk.w & 0xFFFF]);
    }
    __syncthreads();

    // phase 4: sgcn = agg * deg_in^-1/2 + b -> ws
    {
        int dg = sdi[t]; if (dg < 1) dg = 1;
        sgcn[g * Nn + t] = ssc[t] / sqrtf((float)dg) + b[0];
    }
}

// ---------------------------------------------------------------------------
// K3: 2048 blocks x 256 threads — distances + score combine. 16-lane group
// per 2 rows, all 8 feature loads hoisted. (Verified round-3 code, unchanged.)
// ---------------------------------------------------------------------------
__global__ __launch_bounds__(256) void k_score(
        const float* __restrict__ f, const float* __restrict__ c0,
        const float* __restrict__ c1, const float* __restrict__ sgcn,
        const int* __restrict__ label, const float* __restrict__ lw,
        const float* __restrict__ lb, float* __restrict__ sflat) {
    int t = threadIdx.x;
    int gid = t >> 4, sub = t & 15;
    int row0 = blockIdx.x * 32 + gid * 2;       // block spans 32 rows (one graph)
    int g = row0 >> 10;
    const float4* f4 = (const float4*)f;
    float4 c0r[4], c1r[4];
    #pragma unroll
    for (int it = 0; it < 4; ++it) {
        c0r[it] = ((const float4*)c0)[it * 16 + sub];
        c1r[it] = ((const float4*)c1)[it * 16 + sub];
    }
    float sgn = label[g] ? 1.f : -1.f;
    float lw0 = lw[0], lw1 = lw[1], lb0 = lb[0];
    float4 v[2][4];
    #pragma unroll
    for (int r = 0; r < 2; ++r) {
        size_t bofs = (size_t)(row0 + r) * 64;
        #pragma unroll
        for (int it = 0; it < 4; ++it) v[r][it] = f4[bofs + it * 16 + sub];
    }
    #pragma unroll
    for (int r = 0; r < 2; ++r) {
        float a0 = 0.f, a1 = 0.f;
        #pragma unroll
        for (int it = 0; it < 4; ++it) {
            float dx;
            dx = v[r][it].x - c0r[it].x; a0 += dx * dx;
            dx = v[r][it].y - c0r[it].y; a0 += dx * dx;
            dx = v[r][it].z - c0r[it].z; a0 += dx * dx;
            dx = v[r][it].w - c0r[it].w; a0 += dx * dx;
            dx = v[r][it].x - c1r[it].x; a1 += dx * dx;
            dx = v[r][it].y - c1r[it].y; a1 += dx * dx;
            dx = v[r][it].z - c1r[it].z; a1 += dx * dx;
            dx = v[r][it].w - c1r[it].w; a1 += dx * dx;
        }
        #pragma unroll
        for (int o = 1; o < 16; o <<= 1) {
            a0 += __shfl_xor(a0, o);
            a1 += __shfl_xor(a1, o);
        }
        if (sub == 0) {
            int row = row0 + r;
            float sdist = (sqrtf(a0) - sqrtf(a1)) * sgn;
            sflat[row] = sgcn[row] * lw0 + sdist * lw1 + lb0;
        }
    }
}

// ---------------------------------------------------------------------------
// K4: one block (512 threads) per graph: bitonic sort of packed u64 keys,
// perm + complement + softmax partials. (Verified, unchanged.)
// ---------------------------------------------------------------------------
__global__ __launch_bounds__(512) void k_topk(
        const float* __restrict__ sflat, int* __restrict__ permI,
        int* __restrict__ pcomI, float* __restrict__ out,
        float* __restrict__ redM, float* __restrict__ redS) {
    __shared__ unsigned long long sk[1024];
    __shared__ int   sflag[1024];
    __shared__ int   swave[8];
    __shared__ float sred[16];
    int g = blockIdx.x, t = threadIdx.x;
    int lane = t & 63, w = t >> 6;
    float v0 = sflat[g * Nn + t];
    float v1 = sflat[g * Nn + t + 512];
    unsigned u0 = __float_as_uint(v0);
    unsigned u1 = __float_as_uint(v1);
    unsigned o0 = u0 ^ ((u0 >> 31) ? 0xFFFFFFFFu : 0x80000000u);
    unsigned o1 = u1 ^ ((u1 >> 31) ? 0xFFFFFFFFu : 0x80000000u);
    sk[t]       = ((unsigned long long)o0 << 32) | (unsigned)(1023 - t);
    sk[t + 512] = ((unsigned long long)o1 << 32) | (unsigned)(1023 - (t + 512));
    __syncthreads();
    for (int k = 2; k <= 1024; k <<= 1) {
        for (int j = k >> 1; j > 0; j >>= 1) {
            int l = ((t & ~(j - 1)) << 1) | (t & (j - 1));
            int r = l | j;
            unsigned long long a = sk[l], bk = sk[r];
            bool up = ((l & k) == 0);
            if ((a < bk) == up) { sk[l] = bk; sk[r] = a; }
            __syncthreads();
        }
    }
    sflag[t] = 1; sflag[t + 512] = 1;
    __syncthreads();
    {
        int loc = 1023 - (int)(sk[t] & 0xFFFFFFFFu);
        sflag[loc] = 0;
        int gi = g * Nn + loc;
        permI[g * Kk + t] = gi;
        out[OFF_PERM + g * Kk + t] = (float)gi;
    }
    __syncthreads();
    int f0 = sflag[2 * t], f1 = sflag[2 * t + 1];
    int f2 = f0 + f1;
    int inc = f2;
    for (int o = 1; o < 64; o <<= 1) {
        int y = __shfl_up(inc, o);
        if (lane >= o) inc += y;
    }
    if (lane == 63) swave[w] = inc;
    __syncthreads();
    if (t < 8) {
        int a = swave[t];
        for (int o = 1; o < 8; o <<= 1) {
            int y = __shfl_up(a, o);
            if (t >= o) a += y;
        }
        swave[t] = a;
    }
    __syncthreads();
    int basep = ((w > 0) ? swave[w - 1] : 0) + (inc - f2);
    if (f0) {
        int gi = g * Nn + 2 * t;
        pcomI[g * Kk + basep] = gi;
        out[OFF_PCOM + g * Kk + basep] = (float)gi;
    }
    if (f1) {
        int pos = basep + f0;
        int gi = g * Nn + 2 * t + 1;
        pcomI[g * Kk + pos] = gi;
        out[OFF_PCOM + g * Kk + pos] = (float)gi;
    }
    float m = fmaxf(v0, v1);
    for (int o = 32; o > 0; o >>= 1) m = fmaxf(m, __shfl_xor(m, o));
    if (lane == 0) sred[w] = m;
    __syncthreads();
    if (t < 8) {
        float a = sred[t];
        for (int o = 4; o > 0; o >>= 1) a = fmaxf(a, __shfl_xor(a, o));
        if (t == 0) sred[0] = a;
    }
    __syncthreads();
    m = sred[0];
    float s = expf(v0 - m) + expf(v1 - m);
    for (int o = 32; o > 0; o >>= 1) s += __shfl_xor(s, o);
    if (lane == 0) sred[8 + w] = s;
    __syncthreads();
    if (t < 8) {
        float a = sred[8 + t];
        for (int o = 4; o > 0; o >>= 1) a += __shfl_xor(a, o);
        if (t == 0) { redM[g] = m; redS[g] = a; }
    }
}

// ---------------------------------------------------------------------------
// K5: 2048 blocks x 256 threads, 32 rows/block (8 per wave, batched chains):
// gather rows * tanh + softmax write; 64-pair softmax combine per block.
// ---------------------------------------------------------------------------
__global__ __launch_bounds__(256) void k_write(
        const float* __restrict__ f, const int* __restrict__ permI,
        const int* __restrict__ pcomI, const float* __restrict__ sflat,
        const float* __restrict__ redM, const float* __restrict__ redS,
        float* __restrict__ out) {
    __shared__ float sMS[2];
    int t = threadIdx.x;
    if (t < 64) {
        float m = redM[t];
        float mm = m;
        for (int o = 32; o > 0; o >>= 1) mm = fmaxf(mm, __shfl_xor(mm, o));
        float s = redS[t] * expf(m - mm);
        for (int o = 32; o > 0; o >>= 1) s += __shfl_xor(s, o);
        if (t == 0) { sMS[0] = mm; sMS[1] = s; }
    }
    __syncthreads();
    float M = sMS[0], S = sMS[1];
    if (t < 32) {
        int i = blockIdx.x * 32 + t;
        out[OFF_SOFT + i] = expf(sflat[i] - M) / S;
    }
    int w = t >> 6, lane = t & 63;
    int j0 = blockIdx.x * 32 + w * 8;
    int rows[8];
    float tv[8];
    #pragma unroll
    for (int i = 0; i < 8; ++i) {
        int j = j0 + i;
        rows[i] = (j < 32768) ? permI[j] : pcomI[j - 32768];
    }
    #pragma unroll
    for (int i = 0; i < 8; ++i) tv[i] = sflat[rows[i]];
    #pragma unroll
    for (int i = 0; i < 8; ++i) tv[i] = tanhf(tv[i]);
    const float4* f4 = (const float4*)f;
    float4* o4 = (float4*)out;
    float4 v[8];
    #pragma unroll
    for (int i = 0; i < 8; ++i) v[i] = f4[(size_t)rows[i] * 64 + lane];
    #pragma unroll
    for (int i = 0; i < 8; ++i) {
        o4[(size_t)(j0 + i) * 64 + lane] =
            make_float4(v[i].x * tv[i], v[i].y * tv[i], v[i].z * tv[i], v[i].w * tv[i]);
    }
}

extern "C" void kernel_launch(void* const* d_in, const int* in_sizes, int n_in,
                              void* d_out, int out_size, void* d_ws, size_t ws_size,
                              hipStream_t stream) {
    const float* feature = (const float*)d_in[0];
    const int*   src     = (const int*)d_in[1];
    const int*   dst     = (const int*)d_in[2];
    const int*   label   = (const int*)d_in[3];
    const float* W       = (const float*)d_in[4];
    const float* b       = (const float*)d_in[5];
    const float* lw      = (const float*)d_in[6];
    const float* lb      = (const float*)d_in[7];
    float* out = (float*)d_out;
    char*  ws  = (char*)d_ws;

    float* h0    = (float*)(ws + WS_H0);
    float* sflat = (float*)(ws + WS_SFLAT);
    float* gpart = (float*)(ws + WS_GPART);
    float* redM  = (float*)(ws + WS_REDM);
    float* redS  = (float*)(ws + WS_REDS);
    float* c0    = (float*)(ws + WS_C0);
    float* c1    = (float*)(ws + WS_C1);
    int*   permI = (int*)(ws + WS_PERMI);
    int*   pcomI = (int*)(ws + WS_PCOMI);
    float* sgcn  = (float*)(ws + WS_SGCN);

    k_col  <<<1024, 256,  0, stream>>>(feature, W, gpart, h0);
    k_edge <<<Bg,   1024, 0, stream>>>(src, dst, label, h0, gpart, b, sgcn, c0, c1);
    k_score<<<2048, 256,  0, stream>>>(feature, c0, c1, sgcn, label, lw, lb, sflat);
    k_topk <<<Bg,   512,  0, stream>>>(sflat, permI, pcomI, out, redM, redS);
    k_write<<<2048, 256,  0, stream>>>(feature, permI, pcomI, sflat, redM, redS, out);
}

// Round 7
// 194.260 us; speedup vs baseline: 1.5908x; 1.0267x over previous
//
#include <hip/hip_runtime.h>
#include <math.h>

#define Bg   64
#define Nn   1024
#define Dd   256
#define EPG  16384               // edges per graph
#define NT   (Bg * Nn)           // 65536 nodes
#define Kk   512

// d_out float offsets
#define OFF_DIS   0
#define OFF_COM   8388608
#define OFF_PERM  16777216
#define OFF_PCOM  16809984
#define OFF_SOFT  16842752

// ws byte offsets (~7 MB used)
#define WS_H0     0
#define WS_SFLAT  (NT * 4)
#define WS_GPART  (NT * 4 * 2)                 // 1024 blocks * 256 floats = 1 MB
#define WS_REDM   (WS_GPART + 1024 * 256 * 4)  // 64 floats
#define WS_REDS   (WS_REDM + 256)              // 64 floats
#define WS_C0     (WS_REDS + 256)              // 256 floats
#define WS_C1     (WS_C0 + 1024)               // 256 floats
#define WS_PERMI  (WS_C1 + 1024)
#define WS_PCOMI  (WS_PERMI + 32768 * 4)
#define WS_SGCN   (WS_PCOMI + 32768 * 4)       // NT floats
#define WS_EPACK  (WS_SGCN + NT * 4)           // Bg*EPG uints = 4 MB
#define WS_DO     (WS_EPACK + Bg * EPG * 4)    // NT ints
#define WS_DI     (WS_DO + NT * 4)             // NT ints

// ---------------------------------------------------------------------------
// K1: 1088 blocks x 256 threads.
//   blocks 0..1023  : column sums + h0 = f @ W (verified round-3/5 code).
//   blocks 1024..1087: edge staging per graph — pack epack, full degrees
//                      (no h0 dependency; overlaps the feature read).
// ---------------------------------------------------------------------------
__global__ __launch_bounds__(256) void k_mix(
        const float* __restrict__ f, const float* __restrict__ W,
        const int* __restrict__ src, const int* __restrict__ dst,
        float* __restrict__ gpart, float* __restrict__ h0,
        unsigned* __restrict__ epack, int* __restrict__ dout,
        int* __restrict__ dinn) {
    __shared__ alignas(16) char smem[16384];
    int blk = blockIdx.x, t = threadIdx.x;
    if (blk < 1024) {
        float4* scol4 = (float4*)smem;          // 16 groups x 64 float4-cols
        int gid = t >> 4, sub = t & 15;
        int base = blk * 64 + gid * 4;
        const float4* f4 = (const float4*)f;
        const float4* W4 = (const float4*)W;
        float4 w[4];
        #pragma unroll
        for (int it = 0; it < 4; ++it) w[it] = W4[it * 16 + sub];
        float4 cs[4];
        #pragma unroll
        for (int it = 0; it < 4; ++it) cs[it] = make_float4(0.f, 0.f, 0.f, 0.f);
        float4 v[4][4];
        #pragma unroll
        for (int k = 0; k < 4; ++k) {
            size_t bofs = (size_t)(base + k) * 64;
            #pragma unroll
            for (int it = 0; it < 4; ++it) v[k][it] = f4[bofs + it * 16 + sub];
        }
        #pragma unroll
        for (int k = 0; k < 4; ++k) {
            float d = 0.f;
            #pragma unroll
            for (int it = 0; it < 4; ++it) {
                cs[it].x += v[k][it].x; cs[it].y += v[k][it].y;
                cs[it].z += v[k][it].z; cs[it].w += v[k][it].w;
                d += v[k][it].x * w[it].x + v[k][it].y * w[it].y
                   + v[k][it].z * w[it].z + v[k][it].w * w[it].w;
            }
            #pragma unroll
            for (int o = 1; o < 16; o <<= 1) d += __shfl_xor(d, o);
            if (sub == 0) h0[base + k] = d;
        }
        #pragma unroll
        for (int it = 0; it < 4; ++it) scol4[gid * 64 + it * 16 + sub] = cs[it];
        __syncthreads();
        if (t < 64) {
            float4 s = make_float4(0.f, 0.f, 0.f, 0.f);
            #pragma unroll
            for (int g2 = 0; g2 < 16; ++g2) {
                float4 u = scol4[g2 * 64 + t];
                s.x += u.x; s.y += u.y; s.z += u.z; s.w += u.w;
            }
            ((float4*)(gpart + blk * Dd))[t] = s;
        }
    } else {
        int* sdo = (int*)smem;                  // [1024]
        int* sdi = (int*)(smem + 4096);         // [1024]
        int g = blk - 1024;
        #pragma unroll
        for (int j = 0; j < 4; ++j) { sdo[t + j * 256] = 0; sdi[t + j * 256] = 0; }
        __syncthreads();
        const int4* s4 = (const int4*)(src + g * EPG);
        const int4* d4 = (const int4*)(dst + g * EPG);
        uint4* p4 = (uint4*)(epack + g * EPG);
        #pragma unroll
        for (int i = t; i < EPG / 4; i += 256) {
            int4 ss = s4[i];
            int4 dd = d4[i];
            int s0 = ss.x & (Nn - 1), s1 = ss.y & (Nn - 1), s2 = ss.z & (Nn - 1), s3 = ss.w & (Nn - 1);
            int e0 = dd.x & (Nn - 1), e1 = dd.y & (Nn - 1), e2 = dd.z & (Nn - 1), e3 = dd.w & (Nn - 1);
            uint4 pk;
            pk.x = (unsigned)(s0 | (e0 << 16));
            pk.y = (unsigned)(s1 | (e1 << 16));
            pk.z = (unsigned)(s2 | (e2 << 16));
            pk.w = (unsigned)(s3 | (e3 << 16));
            p4[i] = pk;
            atomicAdd(&sdo[s0], 1); atomicAdd(&sdo[s1], 1);
            atomicAdd(&sdo[s2], 1); atomicAdd(&sdo[s3], 1);
            atomicAdd(&sdi[e0], 1); atomicAdd(&sdi[e1], 1);
            atomicAdd(&sdi[e2], 1); atomicAdd(&sdi[e3], 1);
        }
        __syncthreads();
        #pragma unroll
        for (int j = 0; j < 4; ++j) {
            dout[g * Nn + t + j * 256] = sdo[t + j * 256];
            dinn[g * Nn + t + j * 256] = sdi[t + j * 256];
        }
    }
}

// ---------------------------------------------------------------------------
// K2: 65 blocks x 1024 threads.
//   blocks 0..63: shn = h0*deg_out^-1/2, scatter epack into LDS, sgcn -> ws.
//   block 64    : class centers from gpart (concurrent, no straggler).
// ---------------------------------------------------------------------------
__global__ __launch_bounds__(1024) void k_edge2(
        const unsigned* __restrict__ epack, const int* __restrict__ dout,
        const int* __restrict__ dinn, const int* __restrict__ label,
        const float* __restrict__ h0, const float* __restrict__ gpart,
        const float* __restrict__ b, float* __restrict__ sgcn,
        float* __restrict__ c0, float* __restrict__ c1) {
    __shared__ float shn[1024];
    __shared__ float ssc[1024];
    __shared__ float sc0[1024];
    __shared__ float sc1[1024];
    int blk = blockIdx.x, t = threadIdx.x;
    if (blk < 64) {
        int g = blk;
        {
            int dg = dout[g * Nn + t]; if (dg < 1) dg = 1;
            shn[t] = h0[g * Nn + t] / sqrtf((float)dg);
            ssc[t] = 0.f;
        }
        __syncthreads();
        const uint4* p4 = (const uint4*)(epack + g * EPG);
        #pragma unroll
        for (int i = t; i < EPG / 4; i += 1024) {
            uint4 pk = p4[i];
            atomicAdd(&ssc[pk.x >> 16], shn[pk.x & 0xFFFF]);
            atomicAdd(&ssc[pk.y >> 16], shn[pk.y & 0xFFFF]);
            atomicAdd(&ssc[pk.z >> 16], shn[pk.z & 0xFFFF]);
            atomicAdd(&ssc[pk.w >> 16], shn[pk.w & 0xFFFF]);
        }
        __syncthreads();
        {
            int dg = dinn[g * Nn + t]; if (dg < 1) dg = 1;
            sgcn[g * Nn + t] = ssc[t] / sqrtf((float)dg) + b[0];
        }
    } else {
        // centers: 4 chunks x 16 graphs, coalesced over columns
        int col = t & 255, chunk = t >> 8;
        float a0 = 0.f, a1 = 0.f;
        for (int gg = chunk * 16; gg < chunk * 16 + 16; ++gg) {
            float v = 0.f;
            #pragma unroll
            for (int p = 0; p < 16; ++p) v += gpart[(gg * 16 + p) * Dd + col];
            if (label[gg]) a1 += v; else a0 += v;
        }
        sc0[t] = a0; sc1[t] = a1;
        __syncthreads();
        if (t < Dd) {
            int n1 = 0;
            for (int gg = 0; gg < Bg; ++gg) n1 += label[gg];
            float fn1 = fmaxf((float)n1, 1.f);
            float fn0 = fmaxf((float)(Bg - n1), 1.f);
            float s0 = sc0[t] + sc0[256 + t] + sc0[512 + t] + sc0[768 + t];
            float s1 = sc1[t] + sc1[256 + t] + sc1[512 + t] + sc1[768 + t];
            c0[t] = s0 * (1.f / (float)Nn) / fn0;
            c1[t] = s1 * (1.f / (float)Nn) / fn1;
        }
    }
}

// ---------------------------------------------------------------------------
// K3: 2048 blocks x 256 threads — distances + score combine. 16-lane group
// per 2 rows, all 8 feature loads hoisted. (Verified, unchanged.)
// ---------------------------------------------------------------------------
__global__ __launch_bounds__(256) void k_score(
        const float* __restrict__ f, const float* __restrict__ c0,
        const float* __restrict__ c1, const float* __restrict__ sgcn,
        const int* __restrict__ label, const float* __restrict__ lw,
        const float* __restrict__ lb, float* __restrict__ sflat) {
    int t = threadIdx.x;
    int gid = t >> 4, sub = t & 15;
    int row0 = blockIdx.x * 32 + gid * 2;       // block spans 32 rows (one graph)
    int g = row0 >> 10;
    const float4* f4 = (const float4*)f;
    float4 c0r[4], c1r[4];
    #pragma unroll
    for (int it = 0; it < 4; ++it) {
        c0r[it] = ((const float4*)c0)[it * 16 + sub];
        c1r[it] = ((const float4*)c1)[it * 16 + sub];
    }
    float sgn = label[g] ? 1.f : -1.f;
    float lw0 = lw[0], lw1 = lw[1], lb0 = lb[0];
    float4 v[2][4];
    #pragma unroll
    for (int r = 0; r < 2; ++r) {
        size_t bofs = (size_t)(row0 + r) * 64;
        #pragma unroll
        for (int it = 0; it < 4; ++it) v[r][it] = f4[bofs + it * 16 + sub];
    }
    #pragma unroll
    for (int r = 0; r < 2; ++r) {
        float a0 = 0.f, a1 = 0.f;
        #pragma unroll
        for (int it = 0; it < 4; ++it) {
            float dx;
            dx = v[r][it].x - c0r[it].x; a0 += dx * dx;
            dx = v[r][it].y - c0r[it].y; a0 += dx * dx;
            dx = v[r][it].z - c0r[it].z; a0 += dx * dx;
            dx = v[r][it].w - c0r[it].w; a0 += dx * dx;
            dx = v[r][it].x - c1r[it].x; a1 += dx * dx;
            dx = v[r][it].y - c1r[it].y; a1 += dx * dx;
            dx = v[r][it].z - c1r[it].z; a1 += dx * dx;
            dx = v[r][it].w - c1r[it].w; a1 += dx * dx;
        }
        #pragma unroll
        for (int o = 1; o < 16; o <<= 1) {
            a0 += __shfl_xor(a0, o);
            a1 += __shfl_xor(a1, o);
        }
        if (sub == 0) {
            int row = row0 + r;
            float sdist = (sqrtf(a0) - sqrtf(a1)) * sgn;
            sflat[row] = sgcn[row] * lw0 + sdist * lw1 + lb0;
        }
    }
}

// ---------------------------------------------------------------------------
// K4: one block (512 threads) per graph: bitonic sort of packed u64 keys,
// perm + complement + softmax partials. (Verified, unchanged.)
// ---------------------------------------------------------------------------
__global__ __launch_bounds__(512) void k_topk(
        const float* __restrict__ sflat, int* __restrict__ permI,
        int* __restrict__ pcomI, float* __restrict__ out,
        float* __restrict__ redM, float* __restrict__ redS) {
    __shared__ unsigned long long sk[1024];
    __shared__ int   sflag[1024];
    __shared__ int   swave[8];
    __shared__ float sred[16];
    int g = blockIdx.x, t = threadIdx.x;
    int lane = t & 63, w = t >> 6;
    float v0 = sflat[g * Nn + t];
    float v1 = sflat[g * Nn + t + 512];
    unsigned u0 = __float_as_uint(v0);
    unsigned u1 = __float_as_uint(v1);
    unsigned o0 = u0 ^ ((u0 >> 31) ? 0xFFFFFFFFu : 0x80000000u);
    unsigned o1 = u1 ^ ((u1 >> 31) ? 0xFFFFFFFFu : 0x80000000u);
    sk[t]       = ((unsigned long long)o0 << 32) | (unsigned)(1023 - t);
    sk[t + 512] = ((unsigned long long)o1 << 32) | (unsigned)(1023 - (t + 512));
    __syncthreads();
    for (int k = 2; k <= 1024; k <<= 1) {
        for (int j = k >> 1; j > 0; j >>= 1) {
            int l = ((t & ~(j - 1)) << 1) | (t & (j - 1));
            int r = l | j;
            unsigned long long a = sk[l], bk = sk[r];
            bool up = ((l & k) == 0);
            if ((a < bk) == up) { sk[l] = bk; sk[r] = a; }
            __syncthreads();
        }
    }
    sflag[t] = 1; sflag[t + 512] = 1;
    __syncthreads();
    {
        int loc = 1023 - (int)(sk[t] & 0xFFFFFFFFu);
        sflag[loc] = 0;
        int gi = g * Nn + loc;
        permI[g * Kk + t] = gi;
        out[OFF_PERM + g * Kk + t] = (float)gi;
    }
    __syncthreads();
    int f0 = sflag[2 * t], f1 = sflag[2 * t + 1];
    int f2 = f0 + f1;
    int inc = f2;
    for (int o = 1; o < 64; o <<= 1) {
        int y = __shfl_up(inc, o);
        if (lane >= o) inc += y;
    }
    if (lane == 63) swave[w] = inc;
    __syncthreads();
    if (t < 8) {
        int a = swave[t];
        for (int o = 1; o < 8; o <<= 1) {
            int y = __shfl_up(a, o);
            if (t >= o) a += y;
        }
        swave[t] = a;
    }
    __syncthreads();
    int basep = ((w > 0) ? swave[w - 1] : 0) + (inc - f2);
    if (f0) {
        int gi = g * Nn + 2 * t;
        pcomI[g * Kk + basep] = gi;
        out[OFF_PCOM + g * Kk + basep] = (float)gi;
    }
    if (f1) {
        int pos = basep + f0;
        int gi = g * Nn + 2 * t + 1;
        pcomI[g * Kk + pos] = gi;
        out[OFF_PCOM + g * Kk + pos] = (float)gi;
    }
    float m = fmaxf(v0, v1);
    for (int o = 32; o > 0; o >>= 1) m = fmaxf(m, __shfl_xor(m, o));
    if (lane == 0) sred[w] = m;
    __syncthreads();
    if (t < 8) {
        float a = sred[t];
        for (int o = 4; o > 0; o >>= 1) a = fmaxf(a, __shfl_xor(a, o));
        if (t == 0) sred[0] = a;
    }
    __syncthreads();
    m = sred[0];
    float s = expf(v0 - m) + expf(v1 - m);
    for (int o = 32; o > 0; o >>= 1) s += __shfl_xor(s, o);
    if (lane == 0) sred[8 + w] = s;
    __syncthreads();
    if (t < 8) {
        float a = sred[8 + t];
        for (int o = 4; o > 0; o >>= 1) a += __shfl_xor(a, o);
        if (t == 0) { redM[g] = m; redS[g] = a; }
    }
}

// ---------------------------------------------------------------------------
// K5: 2048 blocks x 256 threads, 32 rows/block (8 per wave, batched chains):
// gather rows * tanh + softmax write. (Verified round-5 code, unchanged.)
// ---------------------------------------------------------------------------
__global__ __launch_bounds__(256) void k_write(
        const float* __restrict__ f, const int* __restrict__ permI,
        const int* __restrict__ pcomI, const float* __restrict__ sflat,
        const float* __restrict__ redM, const float* __restrict__ redS,
        float* __restrict__ out) {
    __shared__ float sMS[2];
    int t = threadIdx.x;
    if (t < 64) {
        float m = redM[t];
        float mm = m;
        for (int o = 32; o > 0; o >>= 1) mm = fmaxf(mm, __shfl_xor(mm, o));
        float s = redS[t] * expf(m - mm);
        for (int o = 32; o > 0; o >>= 1) s += __shfl_xor(s, o);
        if (t == 0) { sMS[0] = mm; sMS[1] = s; }
    }
    __syncthreads();
    float M = sMS[0], S = sMS[1];
    if (t < 32) {
        int i = blockIdx.x * 32 + t;
        out[OFF_SOFT + i] = expf(sflat[i] - M) / S;
    }
    int w = t >> 6, lane = t & 63;
    int j0 = blockIdx.x * 32 + w * 8;
    int rows[8];
    float tv[8];
    #pragma unroll
    for (int i = 0; i < 8; ++i) {
        int j = j0 + i;
        rows[i] = (j < 32768) ? permI[j] : pcomI[j - 32768];
    }
    #pragma unroll
    for (int i = 0; i < 8; ++i) tv[i] = sflat[rows[i]];
    #pragma unroll
    for (int i = 0; i < 8; ++i) tv[i] = tanhf(tv[i]);
    const float4* f4 = (const float4*)f;
    float4* o4 = (float4*)out;
    float4 v[8];
    #pragma unroll
    for (int i = 0; i < 8; ++i) v[i] = f4[(size_t)rows[i] * 64 + lane];
    #pragma unroll
    for (int i = 0; i < 8; ++i) {
        o4[(size_t)(j0 + i) * 64 + lane] =
            make_float4(v[i].x * tv[i], v[i].y * tv[i], v[i].z * tv[i], v[i].w * tv[i]);
    }
}

extern "C" void kernel_launch(void* const* d_in, const int* in_sizes, int n_in,
                              void* d_out, int out_size, void* d_ws, size_t ws_size,
                              hipStream_t stream) {
    const float* feature = (const float*)d_in[0];
    const int*   src     = (const int*)d_in[1];
    const int*   dst     = (const int*)d_in[2];
    const int*   label   = (const int*)d_in[3];
    const float* W       = (const float*)d_in[4];
    const float* b       = (const float*)d_in[5];
    const float* lw      = (const float*)d_in[6];
    const float* lb      = (const float*)d_in[7];
    float* out = (float*)d_out;
    char*  ws  = (char*)d_ws;

    float*    h0    = (float*)(ws + WS_H0);
    float*    sflat = (float*)(ws + WS_SFLAT);
    float*    gpart = (float*)(ws + WS_GPART);
    float*    redM  = (float*)(ws + WS_REDM);
    float*    redS  = (float*)(ws + WS_REDS);
    float*    c0    = (float*)(ws + WS_C0);
    float*    c1    = (float*)(ws + WS_C1);
    int*      permI = (int*)(ws + WS_PERMI);
    int*      pcomI = (int*)(ws + WS_PCOMI);
    float*    sgcn  = (float*)(ws + WS_SGCN);
    unsigned* epack = (unsigned*)(ws + WS_EPACK);
    int*      dout  = (int*)(ws + WS_DO);
    int*      dinn  = (int*)(ws + WS_DI);

    k_mix  <<<1088, 256,  0, stream>>>(feature, W, src, dst, gpart, h0, epack, dout, dinn);
    k_edge2<<<65,   1024, 0, stream>>>(epack, dout, dinn, label, h0, gpart, b, sgcn, c0, c1);
    k_score<<<2048, 256,  0, stream>>>(feature, c0, c1, sgcn, label, lw, lb, sflat);
    k_topk <<<Bg,   512,  0, stream>>>(sflat, permI, pcomI, out, redM, redS);
    k_write<<<2048, 256,  0, stream>>>(feature, permI, pcomI, sflat, redM, redS, out);
}